// Round 3
// baseline (1871.030 us; speedup 1.0000x reference)
//
#include <hip/hip_runtime.h>
#include <hip/hip_bf16.h>

// ---------------------------------------------------------------------------
// TGN neighbor attention, restructured:
//   score[n,j,h] = (a_h.ne_j + b_h.re_j + c_h.et_j + q_h.bk_h)/sqrt(128)
//   with a_h = Wk1_h^T q_h etc. (dual trick: per-edge matmuls -> dot products)
//   softmax is over the 2 HEADS per edge (reference axis=-1!). Masked edges
//   get att=(0.5,0.5) and still contribute.
//   logits = sum_r CW_r @ S_r + satt_h*cb_h + c10   (Wv,Wo,Wc folded into
//   6 composites CW_r of shape 10x128; S_r = att-weighted sums of ne/re/et)
// Kd: dtype detection (node_data i32/i64, mask u8/i32/i64/f32) -> flags in ws
// K0: constants (qbias, CW, cb, c10)
// K1: per-node q -> a,b,c dual table (bf16, ws). LDS 49664 B (<64KB cap).
// K2: grid-strided, 1 node/wave/iter; gathers + 2-head softmax + epilogue.
// ---------------------------------------------------------------------------

#define N_NODES 100000
#define EMB 128
#define NBR 20
#define CLS 10

// ws float-offsets for the small constant region
#define OFF_QBIAS 0            // 128
#define OFF_CW    128          // 6*10*128 = 7680, layout ((r*10+c)*128+d)
#define OFF_CB    (128 + 7680) // 20: [h][c]
#define OFF_C10   (OFF_CB + 20)// 10
#define OFF_FLAGS 8000         // 2 ints (byte off 32000)
#define ABC_BYTE_OFF 32768     // bf16 ABC table starts here

#define RSQRT128 0.08838834764831845f

__device__ __forceinline__ float2 load2bf(const __hip_bfloat16* p) {
  ushort2 u = *reinterpret_cast<const ushort2*>(p);
  float2 f;
  f.x = __uint_as_float(((unsigned)u.x) << 16);
  f.y = __uint_as_float(((unsigned)u.y) << 16);
  return f;
}

// ---- dtype-flexible loads (flags decided by tgn_detect at runtime) --------
__device__ __forceinline__ int load_node(const void* nd, size_t idx, int is64) {
  if (is64) return (int)((const long long*)nd)[idx];
  return ((const int*)nd)[idx];
}
// mode: 0=u8, 1=i32, 2=i64, 3=f32
__device__ __forceinline__ int load_mask(const void* m, size_t idx, int mode) {
  if (mode == 0) return ((const unsigned char*)m)[idx] != 0;
  if (mode == 1) return ((const int*)m)[idx] != 0;
  if (mode == 2) return ((const long long*)m)[idx] != 0;
  return ((const float*)m)[idx] != 0.0f;
}

// ---------------------------------------------------------------------------
// Kd: runtime dtype detection. node_data in [0,1e5): int64 => every odd i32
// word is 0. Mask u8: random 0/1 at all byte positions; i32: nonzero bytes
// only at offset%4==0; i64: only offset%8==0; f32: bytes >1 (0x3f800000).
// ---------------------------------------------------------------------------
__global__ __launch_bounds__(256) void tgn_detect(
    const int* __restrict__ nd, const unsigned char* __restrict__ m,
    int* __restrict__ flags)
{
  __shared__ int s_odd, s_b123, s_b4, s_bgt;
  const int tid = threadIdx.x;
  if (tid == 0) { s_odd = 0; s_b123 = 0; s_b4 = 0; s_bgt = 0; }
  __syncthreads();
  int odd = 0;
  for (int i = 2 * tid + 1; i < 4096; i += 512) odd |= nd[i];
  int b123 = 0, b4 = 0, bgt = 0;
  for (int i = tid * 4; i < 8192; i += 1024) {
    b123 |= m[i + 1] | m[i + 2] | m[i + 3];
    bgt |= (m[i] > 1) | (m[i + 1] > 1) | (m[i + 2] > 1) | (m[i + 3] > 1);
  }
  for (int i = tid * 8 + 4; i < 8192; i += 2048) b4 |= m[i];
  if (odd) atomicOr(&s_odd, 1);
  if (b123) atomicOr(&s_b123, 1);
  if (b4) atomicOr(&s_b4, 1);
  if (bgt) atomicOr(&s_bgt, 1);
  __syncthreads();
  if (tid == 0) {
    flags[0] = (s_odd == 0) ? 1 : 0;  // node_data is int64
    flags[1] = s_bgt ? 3 : (s_b123 ? 0 : (s_b4 ? 1 : 2));
  }
}

// ---------------------------------------------------------------------------
// K0: one block. qbias = Wq[:,128:]@cos(time_b)+bq ; M = Wc@Wo ;
// CW[r=arr*2+h] = M_h @ Wv[h-rows, arr-block] ; cb[h] = M_h@bv_h ; c10 = Wc@bo+bc
// ---------------------------------------------------------------------------
__global__ __launch_bounds__(256) void tgn_k0_prep(
    const float* __restrict__ Wq, const float* __restrict__ bq,
    const float* __restrict__ time_b,
    const float* __restrict__ Wv, const float* __restrict__ bv,
    const float* __restrict__ Wo, const float* __restrict__ bo,
    const float* __restrict__ Wc, const float* __restrict__ bc,
    float* __restrict__ wsf)
{
  __shared__ float ccos[128];
  __shared__ float sM[10 * 128];
  const int tid = threadIdx.x;
  if (tid < 128) ccos[tid] = cosf(time_b[tid]);
  __syncthreads();
  if (tid < 128) {
    float s = bq[tid];
    for (int j = 0; j < 128; ++j) s += Wq[tid * 256 + 128 + j] * ccos[j];
    wsf[OFF_QBIAS + tid] = s;
  }
  for (int idx = tid; idx < 1280; idx += 256) {   // M = Wc @ Wo  (10x128)
    int c = idx >> 7, i = idx & 127;
    float s = 0.f;
    for (int k = 0; k < 128; ++k) s += Wc[c * 128 + k] * Wo[k * 128 + i];
    sM[idx] = s;
  }
  __syncthreads();
  for (int idx = tid; idx < 7680; idx += 256) {   // CW composites
    int r = idx / 1280;
    int c = (idx >> 7) % 10;
    int d = idx & 127;
    int arr = r >> 1, h = r & 1;
    float s = 0.f;
    for (int k = 0; k < 64; ++k)
      s += sM[c * 128 + h * 64 + k] * Wv[(h * 64 + k) * 384 + arr * 128 + d];
    wsf[OFF_CW + idx] = s;
  }
  if (tid < 20) {                                  // cb[h][c]
    int h = tid / 10, c = tid % 10;
    float s = 0.f;
    for (int k = 0; k < 64; ++k) s += sM[c * 128 + h * 64 + k] * bv[h * 64 + k];
    wsf[OFF_CB + tid] = s;
  }
  if (tid < 10) {                                  // c10 = Wc@bo + bc
    float s = 0.f;
    for (int k = 0; k < 128; ++k) s += Wc[tid * 128 + k] * bo[k];
    wsf[OFF_C10 + tid] = s + bc[tid];
  }
}

// ---------------------------------------------------------------------------
// K1: 32 nodes/block. Phase1: q = Wq1@ve + qbias, Wq1 staged in 4 K-chunks
// ([128][33] padded). Phase2 per head: [a|b|c]_h = q_h @ Wk_h, Wk staged in
// 4 j-chunks ([16][385]). Dynamic LDS 12416 floats = 49664 B (<64 KB cap).
//   layout: [0,8320) phase1 {WqS 4224 | veS 4096} / [0,6160) phase2 {WkS}
//           [8320,12416) q_s [32][128]
// ---------------------------------------------------------------------------
__global__ __launch_bounds__(256) void tgn_k1_abc(
    const void* __restrict__ node_data, const float* __restrict__ v_emb,
    const float* __restrict__ Wq, const float* __restrict__ Wk,
    const float* __restrict__ bk, const float* __restrict__ wsf,
    const int* __restrict__ flags, __hip_bfloat16* __restrict__ ABC,
    float* __restrict__ QBK)
{
  extern __shared__ float smem[];
  float* WqS = smem;          // [128][33]
  float* veS = smem + 4224;   // [32][128]
  float* WkS = smem;          // [16][385]
  float* q_s = smem + 8320;   // [32][128]
  __shared__ int sv[32];
  const int tid = threadIdx.x;
  const int base = blockIdx.x * 32;  // 3125 * 32 == 100000 exactly
  const int nd64 = flags[0];

  if (tid < 32) sv[tid] = load_node(node_data, (size_t)(base + tid) * 4, nd64);
  __syncthreads();
  for (int idx = tid; idx < 4096; idx += 256) {
    int n = idx >> 7, i = idx & 127;
    veS[n * 128 + i] = v_emb[(size_t)sv[n] * EMB + i];
  }

  // ---- phase 1: q[32][128] = veS @ Wq1^T + qbias ----
  {
    const int tx = tid & 31, ty = tid >> 5;
    float acc[4][4];
#pragma unroll
    for (int r = 0; r < 4; ++r)
#pragma unroll
      for (int c = 0; c < 4; ++c) acc[r][c] = wsf[OFF_QBIAS + tx + 32 * c];
#pragma unroll 1
    for (int kc = 0; kc < 4; ++kc) {
      __syncthreads();  // kc=0: veS ready; kc>0: prev readers done
      for (int idx = tid; idx < 4096; idx += 256) {
        int o = idx >> 5, kk = idx & 31;
        WqS[o * 33 + kk] = Wq[o * 256 + kc * 32 + kk];
      }
      __syncthreads();
#pragma unroll 4
      for (int i = 0; i < 32; ++i) {
        float wv[4], vv[4];
#pragma unroll
        for (int c = 0; c < 4; ++c) wv[c] = WqS[(tx + 32 * c) * 33 + i];
#pragma unroll
        for (int r = 0; r < 4; ++r) vv[r] = veS[(ty + 8 * r) * 128 + kc * 32 + i];
#pragma unroll
        for (int r = 0; r < 4; ++r)
#pragma unroll
          for (int c = 0; c < 4; ++c) acc[r][c] += vv[r] * wv[c];
      }
    }
#pragma unroll
    for (int r = 0; r < 4; ++r)
#pragma unroll
      for (int c = 0; c < 4; ++c)
        q_s[(ty + 8 * r) * 128 + (tx + 32 * c)] = acc[r][c];
  }

  // ---- phase 2: per head, [a|b|c]_h = q_h @ Wk_h (384 cols) ----
  {
    const int tx = tid & 63, ty = tid >> 6;
#pragma unroll 1
    for (int h = 0; h < 2; ++h) {
      float acc[8][6];
#pragma unroll
      for (int r = 0; r < 8; ++r)
#pragma unroll
        for (int c = 0; c < 6; ++c) acc[r][c] = 0.f;
#pragma unroll 1
      for (int jc = 0; jc < 4; ++jc) {
        __syncthreads();  // first: q_s writes done; later: prev WkS readers done
        for (int idx = tid; idx < 6144; idx += 256) {
          int jj = idx / 384, o = idx - jj * 384;
          WkS[jj * 385 + o] = Wk[(size_t)(h * 64 + jc * 16 + jj) * 384 + o];
        }
        __syncthreads();
#pragma unroll 4
        for (int jj = 0; jj < 16; ++jj) {
          float bb[6], qq[8];
#pragma unroll
          for (int c = 0; c < 6; ++c) bb[c] = WkS[jj * 385 + tx + 64 * c];
#pragma unroll
          for (int r = 0; r < 8; ++r)
            qq[r] = q_s[(ty + 4 * r) * 128 + h * 64 + jc * 16 + jj];
#pragma unroll
          for (int r = 0; r < 8; ++r)
#pragma unroll
            for (int c = 0; c < 6; ++c) acc[r][c] += qq[r] * bb[c];
        }
      }
#pragma unroll
      for (int r = 0; r < 8; ++r) {
        const size_t n = (size_t)(base + ty + 4 * r);
#pragma unroll
        for (int c = 0; c < 6; ++c) {
          int o = tx + 64 * c;
          int arr = o >> 7, d = o & 127;
          ABC[n * 768 + (size_t)(arr * 2 + h) * 128 + d] =
              __float2bfloat16(acc[r][c]);
        }
      }
    }
  }

  if (tid < 64) {  // QBK[n][h] = q_h . bk_h  (q_s stable since phase 1)
    int n = tid >> 1, h = tid & 1;
    float s = 0.f;
    for (int j = 0; j < 64; ++j) s += q_s[n * 128 + h * 64 + j] * bk[h * 64 + j];
    QBK[(size_t)(base + n) * 2 + h] = s;
  }
}

// ---------------------------------------------------------------------------
// K2: 2500 blocks x 4 waves, 10 nodes per wave (grid-strided so cw_s staging
// is amortized 10x). Lane l owns dims {2l, 2l+1}. Depth-4 gather prefetch.
// ---------------------------------------------------------------------------
#define ISSUE(J)                                                            \
  {                                                                         \
    int vv_ = __shfl(e_v, (J), 64);                                         \
    int rr_ = __shfl(e_r, (J), 64);                                         \
    pne[(J) & 3] = *(const float2*)(v_emb + (size_t)vv_ * EMB + 2 * lane);  \
    pre[(J) & 3] = *(const float2*)(r_emb + (size_t)rr_ * EMB + 2 * lane);  \
  }

__global__ __launch_bounds__(256) void tgn_k2_edge(
    const void* __restrict__ node_data, const int* __restrict__ nbr_data,
    const void* __restrict__ nbr_mask,
    const float* __restrict__ v_emb, const float* __restrict__ r_emb,
    const float* __restrict__ time_w, const float* __restrict__ time_b,
    const __hip_bfloat16* __restrict__ ABC, const float* __restrict__ QBK,
    const float* __restrict__ wsf, const float* __restrict__ bc,
    const int* __restrict__ flags, float* __restrict__ out)
{
  __shared__ float cw_s[7680];
  const int tid = threadIdx.x;
  for (int idx = tid; idx < 7680; idx += 256) cw_s[idx] = wsf[OFF_CW + idx];
  __syncthreads();

  const int nd64 = flags[0];
  const int mmode = flags[1];
  const int lane = tid & 63;
  const int gw = blockIdx.x * 4 + (tid >> 6);  // 2500*4 = 10000 waves
  const float2 tw = *(const float2*)(time_w + 2 * lane);
  const float2 tb = *(const float2*)(time_b + 2 * lane);
  const float cb00 = wsf[OFF_CB + 0];  // dummy touch to keep wsf in L2 (cheap)

#pragma unroll 1
  for (int it = 0; it < 10; ++it) {
    const int n = it * 10000 + gw;  // consecutive across waves each iter
    const int t_node = load_node(node_data, (size_t)n * 4 + 2, nd64);

    int e_v = 0, e_r = 0, e_t = 0, e_m = 1;
    if (lane < NBR) {
      const int* p = nbr_data + ((size_t)n * NBR + lane) * 3;
      e_v = p[0]; e_r = p[1]; e_t = p[2];
      e_m = load_mask(nbr_mask, (size_t)n * NBR + lane, mmode);
    }

    float ax[6], ay[6];
#pragma unroll
    for (int r2 = 0; r2 < 6; ++r2) {
      float2 v = load2bf(&ABC[(size_t)n * 768 + (size_t)r2 * 128 + 2 * lane]);
      ax[r2] = v.x; ay[r2] = v.y;
    }
    const float qbk0 = QBK[(size_t)n * 2 + 0];
    const float qbk1 = QBK[(size_t)n * 2 + 1];

    float sx[6] = {0, 0, 0, 0, 0, 0}, sy[6] = {0, 0, 0, 0, 0, 0};
    float satt0 = 0.f, satt1 = 0.f;

    float2 pne[4], pre[4];
    ISSUE(0) ISSUE(1) ISSUE(2) ISSUE(3)

#pragma unroll
    for (int j = 0; j < NBR; ++j) {
      float2 ne = pne[j & 3], re = pre[j & 3];
      int tj = __shfl(e_t, j, 64);
      int mj = __shfl(e_m, j, 64);
      if (j < NBR - 4) ISSUE(j + 4)

      float dt = (float)(t_node - tj);
      // match reference rounding: rn(dt*tw) then rn(+tb); no fma contraction
      float et0 = cosf(__fadd_rn(__fmul_rn(dt, tw.x), tb.x));
      float et1 = cosf(__fadd_rn(__fmul_rn(dt, tw.y), tb.y));

      float p0 = ax[0] * ne.x + ay[0] * ne.y + ax[2] * re.x + ay[2] * re.y +
                 ax[4] * et0 + ay[4] * et1;
      float p1 = ax[1] * ne.x + ay[1] * ne.y + ax[3] * re.x + ay[3] * re.y +
                 ax[5] * et0 + ay[5] * et1;
#pragma unroll
      for (int m = 1; m < 64; m <<= 1) {
        p0 += __shfl_xor(p0, m, 64);
        p1 += __shfl_xor(p1, m, 64);
      }
      float att0, att1;
      if (mj) {          // masked: softmax([-1e9,-1e9]) over heads = (.5,.5)
        att0 = 0.5f; att1 = 0.5f;
      } else {
        float s0 = (p0 + qbk0) * RSQRT128;
        float s1 = (p1 + qbk1) * RSQRT128;
        float mm = fmaxf(s0, s1);
        float e0 = expf(s0 - mm), e1 = expf(s1 - mm);
        float inv = 1.f / (e0 + e1);
        att0 = e0 * inv; att1 = e1 * inv;
      }
      satt0 += att0; satt1 += att1;
      sx[0] += att0 * ne.x; sy[0] += att0 * ne.y;
      sx[1] += att1 * ne.x; sy[1] += att1 * ne.y;
      sx[2] += att0 * re.x; sy[2] += att0 * re.y;
      sx[3] += att1 * re.x; sy[3] += att1 * re.y;
      sx[4] += att0 * et0;  sy[4] += att0 * et1;
      sx[5] += att1 * et0;  sy[5] += att1 * et1;
    }

    unsigned long long alive = __ballot(lane < NBR && !e_m);
    bool flag = (alive == 0ULL);  // all masked -> out zeroed -> logits = bc

    float lg[10];
#pragma unroll
    for (int c = 0; c < 10; ++c) {
      float p = 0.f;
#pragma unroll
      for (int r2 = 0; r2 < 6; ++r2) {
        const float* cwp = &cw_s[(r2 * 10 + c) * 128 + 2 * lane];
        p += cwp[0] * sx[r2] + cwp[1] * sy[r2];
      }
#pragma unroll
      for (int m = 1; m < 64; m <<= 1) p += __shfl_xor(p, m, 64);
      lg[c] = p;
    }
    if (lane == 0) {
#pragma unroll
      for (int c = 0; c < 10; ++c) {
        float v;
        if (flag) v = bc[c];
        else
          v = lg[c] + satt0 * wsf[OFF_CB + c] + satt1 * wsf[OFF_CB + 10 + c] +
              wsf[OFF_C10 + c];
        out[(size_t)n * 10 + c] = v;
      }
    }
  }
  (void)cb00;
}

// ---------------------------------------------------------------------------
extern "C" void kernel_launch(void* const* d_in, const int* in_sizes, int n_in,
                              void* d_out, int out_size, void* d_ws,
                              size_t ws_size, hipStream_t stream)
{
  const void* node_data = d_in[0];
  const int* nbr_data = (const int*)d_in[1];
  const void* nbr_mask = d_in[2];
  const float* v_emb = (const float*)d_in[3];
  const float* r_emb = (const float*)d_in[4];
  const float* time_w = (const float*)d_in[5];
  const float* time_b = (const float*)d_in[6];
  const float* Wq = (const float*)d_in[7];
  const float* bq = (const float*)d_in[8];
  const float* Wk = (const float*)d_in[9];
  const float* bk = (const float*)d_in[10];
  const float* Wv = (const float*)d_in[11];
  const float* bv = (const float*)d_in[12];
  const float* Wo = (const float*)d_in[13];
  const float* bo = (const float*)d_in[14];
  const float* Wc = (const float*)d_in[15];
  const float* bc = (const float*)d_in[16];
  float* out = (float*)d_out;
  float* wsf = (float*)d_ws;
  int* flags = (int*)((char*)d_ws + OFF_FLAGS * sizeof(float));

  __hip_bfloat16* ABC = (__hip_bfloat16*)((char*)d_ws + ABC_BYTE_OFF);
  float* QBK =
      (float*)((char*)d_ws + ABC_BYTE_OFF + (size_t)N_NODES * 768 * 2);

  hipLaunchKernelGGL(tgn_detect, dim3(1), dim3(256), 0, stream,
                     (const int*)node_data, (const unsigned char*)nbr_mask,
                     flags);
  hipLaunchKernelGGL(tgn_k0_prep, dim3(1), dim3(256), 0, stream, Wq, bq,
                     time_b, Wv, bv, Wo, bo, Wc, bc, wsf);
  hipLaunchKernelGGL(tgn_k1_abc, dim3(3125), dim3(256), 12416 * sizeof(float),
                     stream, node_data, v_emb, Wq, Wk, bk, wsf, flags, ABC,
                     QBK);
  hipLaunchKernelGGL(tgn_k2_edge, dim3(2500), dim3(256), 0, stream, node_data,
                     nbr_data, nbr_mask, v_emb, r_emb, time_w, time_b, ABC,
                     QBK, wsf, bc, flags, out);
}

// Round 4
// 1721.491 us; speedup vs baseline: 1.0869x; 1.0869x over previous
//
#include <hip/hip_runtime.h>
#include <hip/hip_bf16.h>

// ---------------------------------------------------------------------------
// TGN neighbor attention. Key algebra:
//   softmax over HEADS(=2) per edge  =>  att0 = sigmoid(s0-s1), att1 = 1-att0
//   => only the DIFFERENCE dual Ad = A1-A0 is needed for scores, where
//      A_h[i] = sum_o q_h[o] * Wk[o,i]  (dual trick), i in [0,384)
//   => Ad = qsign @ Wk with qsign = [-q0 | +q1]  (single pass)
//   s1-s0 = (Ad.keyv + qbkd) / sqrt(128),  qbkd = qsign.bk
//   S_0,arr = att0-weighted sums; S_1,arr = (unweighted) - S_0,arr
//   satt1 = 20 - satt0
//   logits = sum_r CW_r @ S_r + satt0*cb0 + (20-satt0)*cb1 + c10
// Kd: dtype detect (node_data i32/i64, mask u8/i32/i64/f32)
// K0: constants. Kc: v_emb/r_emb -> bf16 tables in ws (L3-resident: total
//     working set 77+51+24 MB < 256 MB Infinity Cache).
// K1: per-node qsign -> Ad table (bf16, [n][384]) + qbkd.
// K2: per-wave-per-node edges: 40-deep gather prefetch, 1 butterfly/edge.
// ---------------------------------------------------------------------------

#define N_NODES 100000
#define EMB 128
#define NBR 20
#define CLS 10

// ws float-offsets for the small constant region
#define OFF_QBIAS 0            // 128
#define OFF_CW    128          // 6*10*128 = 7680, layout ((arr*2+h)*10+c)*128+d
#define OFF_CB    (128 + 7680) // 20: [h][c]
#define OFF_C10   (OFF_CB + 20)// 10
#define OFF_FLAGS 8000         // 2 ints (byte off 32000)
// byte offsets of the big ws tables
#define OFF_ABC 32768ULL                          // 100000*384*2 = 76.8 MB
#define OFF_QBK (OFF_ABC + 100000ULL * 384 * 2)   // 0.4 MB
#define OFF_VBF (OFF_QBK + 100000ULL * 4)         // 25.6 MB
#define OFF_RBF (OFF_VBF + 100000ULL * 128 * 2)   // 25.6 MB

#define RSQRT128 0.08838834764831845f

// round-to-nearest-even f32 -> bf16 bits
__device__ __forceinline__ unsigned short f2bf(float x) {
  unsigned u = __float_as_uint(x);
  return (unsigned short)((u + 0x7fffu + ((u >> 16) & 1u)) >> 16);
}
// unpack 2 bf16 (packed little-endian in a uint) -> float2
__device__ __forceinline__ float2 unpack_bf2(unsigned u) {
  float2 f;
  f.x = __uint_as_float(u << 16);
  f.y = __uint_as_float(u & 0xffff0000u);
  return f;
}

// ---- dtype-flexible loads (flags decided by tgn_detect at runtime) --------
__device__ __forceinline__ int load_node(const void* nd, size_t idx, int is64) {
  if (is64) return (int)((const long long*)nd)[idx];
  return ((const int*)nd)[idx];
}
// mode: 0=u8, 1=i32, 2=i64, 3=f32
__device__ __forceinline__ int load_mask(const void* m, size_t idx, int mode) {
  if (mode == 0) return ((const unsigned char*)m)[idx] != 0;
  if (mode == 1) return ((const int*)m)[idx] != 0;
  if (mode == 2) return ((const long long*)m)[idx] != 0;
  return ((const float*)m)[idx] != 0.0f;
}

// ---------------------------------------------------------------------------
__global__ __launch_bounds__(256) void tgn_detect(
    const int* __restrict__ nd, const unsigned char* __restrict__ m,
    int* __restrict__ flags)
{
  __shared__ int s_odd, s_b123, s_b4, s_bgt;
  const int tid = threadIdx.x;
  if (tid == 0) { s_odd = 0; s_b123 = 0; s_b4 = 0; s_bgt = 0; }
  __syncthreads();
  int odd = 0;
  for (int i = 2 * tid + 1; i < 4096; i += 512) odd |= nd[i];
  int b123 = 0, b4 = 0, bgt = 0;
  for (int i = tid * 4; i < 8192; i += 1024) {
    b123 |= m[i + 1] | m[i + 2] | m[i + 3];
    bgt |= (m[i] > 1) | (m[i + 1] > 1) | (m[i + 2] > 1) | (m[i + 3] > 1);
  }
  for (int i = tid * 8 + 4; i < 8192; i += 2048) b4 |= m[i];
  if (odd) atomicOr(&s_odd, 1);
  if (b123) atomicOr(&s_b123, 1);
  if (b4) atomicOr(&s_b4, 1);
  if (bgt) atomicOr(&s_bgt, 1);
  __syncthreads();
  if (tid == 0) {
    flags[0] = (s_odd == 0) ? 1 : 0;  // node_data is int64
    flags[1] = s_bgt ? 3 : (s_b123 ? 0 : (s_b4 ? 1 : 2));
  }
}

// ---------------------------------------------------------------------------
// Kc: fp32 -> packed bf16x2 table conversion (grid-stride over float2 pairs)
// ---------------------------------------------------------------------------
__global__ __launch_bounds__(256) void tgn_cvt(
    const float* __restrict__ src, unsigned* __restrict__ dst, int npair)
{
  int i = blockIdx.x * 256 + threadIdx.x;
  const int stride = gridDim.x * 256;
  for (; i < npair; i += stride) {
    float2 f = ((const float2*)src)[i];
    dst[i] = (unsigned)f2bf(f.x) | ((unsigned)f2bf(f.y) << 16);
  }
}

// ---------------------------------------------------------------------------
// K0: one block. qbias = Wq[:,128:]@cos(time_b)+bq ; M = Wc@Wo ;
// CW[arr*2+h] = M_h @ Wv[h-rows, arr-block] ; cb[h]=M_h@bv_h ; c10=Wc@bo+bc
// ---------------------------------------------------------------------------
__global__ __launch_bounds__(256) void tgn_k0_prep(
    const float* __restrict__ Wq, const float* __restrict__ bq,
    const float* __restrict__ time_b,
    const float* __restrict__ Wv, const float* __restrict__ bv,
    const float* __restrict__ Wo, const float* __restrict__ bo,
    const float* __restrict__ Wc, const float* __restrict__ bc,
    float* __restrict__ wsf)
{
  __shared__ float ccos[128];
  __shared__ float sM[10 * 128];
  const int tid = threadIdx.x;
  if (tid < 128) ccos[tid] = cosf(time_b[tid]);
  __syncthreads();
  if (tid < 128) {
    float s = bq[tid];
    for (int j = 0; j < 128; ++j) s += Wq[tid * 256 + 128 + j] * ccos[j];
    wsf[OFF_QBIAS + tid] = s;
  }
  for (int idx = tid; idx < 1280; idx += 256) {   // M = Wc @ Wo  (10x128)
    int c = idx >> 7, i = idx & 127;
    float s = 0.f;
    for (int k = 0; k < 128; ++k) s += Wc[c * 128 + k] * Wo[k * 128 + i];
    sM[idx] = s;
  }
  __syncthreads();
  for (int idx = tid; idx < 7680; idx += 256) {   // CW composites
    int r = idx / 1280;
    int c = (idx >> 7) % 10;
    int d = idx & 127;
    int arr = r >> 1, h = r & 1;
    float s = 0.f;
    for (int k = 0; k < 64; ++k)
      s += sM[c * 128 + h * 64 + k] * Wv[(h * 64 + k) * 384 + arr * 128 + d];
    wsf[OFF_CW + idx] = s;
  }
  if (tid < 20) {                                  // cb[h][c]
    int h = tid / 10, c = tid % 10;
    float s = 0.f;
    for (int k = 0; k < 64; ++k) s += sM[c * 128 + h * 64 + k] * bv[h * 64 + k];
    wsf[OFF_CB + tid] = s;
  }
  if (tid < 10) {                                  // c10 = Wc@bo + bc
    float s = 0.f;
    for (int k = 0; k < 128; ++k) s += Wc[tid * 128 + k] * bo[k];
    wsf[OFF_C10 + tid] = s + bc[tid];
  }
}

// ---------------------------------------------------------------------------
// K1: 32 nodes/block.
// Phase1: q = Wq1@ve + qbias (Wq1 staged in 4 K-chunks [128][33]); store
//         qsign into q_s (negate dims<64 = head0).
// Phase2: Ad[32][384] = qsign @ Wk, Wk staged in 8 chunks of 16 rows
//         ([16][385]); store bf16 to ABC[n*384+i].
// QBK[n] = qsign . bk.   Dynamic LDS 12416 floats = 49664 B (<64 KB cap).
// ---------------------------------------------------------------------------
__global__ __launch_bounds__(256) void tgn_k1_abc(
    const void* __restrict__ node_data, const float* __restrict__ v_emb,
    const float* __restrict__ Wq, const float* __restrict__ Wk,
    const float* __restrict__ bk, const float* __restrict__ wsf,
    const int* __restrict__ flags, unsigned short* __restrict__ ABC,
    float* __restrict__ QBK)
{
  extern __shared__ float smem[];
  float* WqS = smem;          // [128][33]
  float* veS = smem + 4224;   // [32][128]
  float* WkS = smem;          // [16][385]
  float* q_s = smem + 8320;   // [32][128]
  __shared__ int sv[32];
  const int tid = threadIdx.x;
  const int base = blockIdx.x * 32;  // 3125 * 32 == 100000 exactly
  const int nd64 = flags[0];

  if (tid < 32) sv[tid] = load_node(node_data, (size_t)(base + tid) * 4, nd64);
  __syncthreads();
  for (int idx = tid; idx < 4096; idx += 256) {
    int n = idx >> 7, i = idx & 127;
    veS[n * 128 + i] = v_emb[(size_t)sv[n] * EMB + i];
  }

  // ---- phase 1: q[32][128] = veS @ Wq1^T + qbias; store with head0 negated
  {
    const int tx = tid & 31, ty = tid >> 5;
    float acc[4][4];
#pragma unroll
    for (int r = 0; r < 4; ++r)
#pragma unroll
      for (int c = 0; c < 4; ++c) acc[r][c] = wsf[OFF_QBIAS + tx + 32 * c];
#pragma unroll 1
    for (int kc = 0; kc < 4; ++kc) {
      __syncthreads();  // kc=0: veS ready; kc>0: prev readers done
      for (int idx = tid; idx < 4096; idx += 256) {
        int o = idx >> 5, kk = idx & 31;
        WqS[o * 33 + kk] = Wq[o * 256 + kc * 32 + kk];
      }
      __syncthreads();
#pragma unroll 4
      for (int i = 0; i < 32; ++i) {
        float wv[4], vv[4];
#pragma unroll
        for (int c = 0; c < 4; ++c) wv[c] = WqS[(tx + 32 * c) * 33 + i];
#pragma unroll
        for (int r = 0; r < 4; ++r) vv[r] = veS[(ty + 8 * r) * 128 + kc * 32 + i];
#pragma unroll
        for (int r = 0; r < 4; ++r)
#pragma unroll
          for (int c = 0; c < 4; ++c) acc[r][c] += vv[r] * wv[c];
      }
    }
#pragma unroll
    for (int r = 0; r < 4; ++r)
#pragma unroll
      for (int c = 0; c < 4; ++c)
        q_s[(ty + 8 * r) * 128 + (tx + 32 * c)] =
            (c < 2) ? -acc[r][c] : acc[r][c];  // cols 0..63 = head0 -> negate
  }

  // ---- phase 2: Ad[32][384] = qsign @ Wk (single pass over 128 q-dims) ----
  {
    const int tx = tid & 63, ty = tid >> 6;
    float acc[8][6];
#pragma unroll
    for (int r = 0; r < 8; ++r)
#pragma unroll
      for (int c = 0; c < 6; ++c) acc[r][c] = 0.f;
#pragma unroll 1
    for (int jc = 0; jc < 8; ++jc) {
      __syncthreads();  // jc=0: q_s writes done; later: prev WkS readers done
      for (int idx = tid; idx < 6144; idx += 256) {
        int jj = idx / 384, o = idx - jj * 384;
        WkS[jj * 385 + o] = Wk[(size_t)(jc * 16 + jj) * 384 + o];
      }
      __syncthreads();
#pragma unroll 4
      for (int jj = 0; jj < 16; ++jj) {
        float bb[6], qq[8];
#pragma unroll
        for (int c = 0; c < 6; ++c) bb[c] = WkS[jj * 385 + tx + 64 * c];
#pragma unroll
        for (int r = 0; r < 8; ++r)
          qq[r] = q_s[(ty + 4 * r) * 128 + jc * 16 + jj];
#pragma unroll
        for (int r = 0; r < 8; ++r)
#pragma unroll
          for (int c = 0; c < 6; ++c) acc[r][c] += qq[r] * bb[c];
      }
    }
#pragma unroll
    for (int r = 0; r < 8; ++r) {
      const size_t n = (size_t)(base + ty + 4 * r);
#pragma unroll
      for (int c = 0; c < 6; ++c)
        ABC[n * 384 + tx + 64 * c] = f2bf(acc[r][c]);
    }
  }

  if (tid < 32) {  // QBK[n] = qsign . bk   (q_s stable since phase 1)
    float s = 0.f;
    for (int j = 0; j < 128; ++j) s += q_s[tid * 128 + j] * bk[j];
    QBK[(size_t)(base + tid)] = s;
  }
}

// ---------------------------------------------------------------------------
// K2: 2500 blocks x 4 waves, 10 nodes per wave. Lane l owns dims {2l,2l+1}.
// All 40 gather loads issued up-front (packed bf16x2 uints). One 6-step
// butterfly per edge (score DIFFERENCE only); att1-sums derived at epilogue.
// ---------------------------------------------------------------------------
__global__ __launch_bounds__(256) void tgn_k2_edge(
    const void* __restrict__ node_data, const int* __restrict__ nbr_data,
    const void* __restrict__ nbr_mask,
    const unsigned* __restrict__ vbf, const unsigned* __restrict__ rbf,
    const float* __restrict__ time_w, const float* __restrict__ time_b,
    const unsigned* __restrict__ abc32, const float* __restrict__ QBK,
    const float* __restrict__ wsf, const float* __restrict__ bc,
    const int* __restrict__ flags, float* __restrict__ out)
{
  __shared__ float cw_s[7680];
  const int tid = threadIdx.x;
  for (int idx = tid; idx < 7680; idx += 256) cw_s[idx] = wsf[OFF_CW + idx];
  __syncthreads();

  const int nd64 = flags[0];
  const int mmode = flags[1];
  const int lane = tid & 63;
  const int gw = blockIdx.x * 4 + (tid >> 6);  // 2500*4 = 10000 waves
  const float2 tw = *(const float2*)(time_w + 2 * lane);
  const float2 tb = *(const float2*)(time_b + 2 * lane);

#pragma unroll 1
  for (int it = 0; it < 10; ++it) {
    const int n = it * 10000 + gw;  // consecutive across waves each iter
    const int t_node = load_node(node_data, (size_t)n * 4 + 2, nd64);

    int e_v = 0, e_r = 0, e_t = 0, e_m = 1;
    if (lane < NBR) {
      const int* p = nbr_data + ((size_t)n * NBR + lane) * 3;
      e_v = p[0]; e_r = p[1]; e_t = p[2];
      e_m = load_mask(nbr_mask, (size_t)n * NBR + lane, mmode);
    }

    // issue ALL 40 gathers up-front (wave-uniform rows; 4B/lane, coalesced)
    unsigned pne_u[NBR], pre_u[NBR];
#pragma unroll
    for (int j = 0; j < NBR; ++j) {
      int vv = __shfl(e_v, j, 64);
      int rr = __shfl(e_r, j, 64);
      pne_u[j] = vbf[(size_t)vv * 64 + lane];
      pre_u[j] = rbf[(size_t)rr * 64 + lane];
    }

    // difference duals (bf16) + scalar dual bias
    float adx[3], ady[3];
#pragma unroll
    for (int a = 0; a < 3; ++a) {
      float2 v = unpack_bf2(abc32[(size_t)n * 192 + a * 64 + lane]);
      adx[a] = v.x; ady[a] = v.y;
    }
    const float qbkd = QBK[n];

    float sux[3] = {0, 0, 0}, suy[3] = {0, 0, 0};
    float swx[3] = {0, 0, 0}, swy[3] = {0, 0, 0};
    float satt0 = 0.f;

#pragma unroll
    for (int j = 0; j < NBR; ++j) {
      float2 ne = unpack_bf2(pne_u[j]);
      float2 re = unpack_bf2(pre_u[j]);
      int tj = __shfl(e_t, j, 64);
      int mj = __shfl(e_m, j, 64);

      float dt = (float)(t_node - tj);
      // match reference rounding: rn(dt*tw) then rn(+tb); no fma contraction
      float et0 = cosf(__fadd_rn(__fmul_rn(dt, tw.x), tb.x));
      float et1 = cosf(__fadd_rn(__fmul_rn(dt, tw.y), tb.y));

      // per-lane partial of (s1-s0) dot
      float pd = adx[0] * ne.x + ady[0] * ne.y + adx[1] * re.x +
                 ady[1] * re.y + adx[2] * et0 + ady[2] * et1;
#pragma unroll
      for (int m = 1; m < 64; m <<= 1) pd += __shfl_xor(pd, m, 64);

      float dlt = (pd + qbkd) * RSQRT128;  // = s1 - s0
      // softmax over 2 heads == sigmoid; masked edges: both -1e9 -> 0.5
      float att0 = mj ? 0.5f : 1.0f / (1.0f + __expf(dlt));
      satt0 += att0;
      sux[0] += ne.x; suy[0] += ne.y;
      sux[1] += re.x; suy[1] += re.y;
      sux[2] += et0;  suy[2] += et1;
      swx[0] += att0 * ne.x; swy[0] += att0 * ne.y;
      swx[1] += att0 * re.x; swy[1] += att0 * re.y;
      swx[2] += att0 * et0;  swy[2] += att0 * et1;
    }

    unsigned long long alive = __ballot(lane < NBR && !e_m);
    bool flag = (alive == 0ULL);  // all masked -> out zeroed -> logits = bc

    // head1 sums = unweighted - head0 sums
    float s1x[3], s1y[3];
#pragma unroll
    for (int a = 0; a < 3; ++a) {
      s1x[a] = sux[a] - swx[a];
      s1y[a] = suy[a] - swy[a];
    }

    float lg[10];
#pragma unroll
    for (int c = 0; c < 10; ++c) {
      float p = 0.f;
#pragma unroll
      for (int a = 0; a < 3; ++a) {
        const float* c0 = &cw_s[((a * 2 + 0) * 10 + c) * 128 + 2 * lane];
        const float* c1 = &cw_s[((a * 2 + 1) * 10 + c) * 128 + 2 * lane];
        p += c0[0] * swx[a] + c0[1] * swy[a] + c1[0] * s1x[a] + c1[1] * s1y[a];
      }
#pragma unroll
      for (int m = 1; m < 64; m <<= 1) p += __shfl_xor(p, m, 64);
      lg[c] = p;
    }
    if (lane == 0) {
      const float satt1 = (float)NBR - satt0;
#pragma unroll
      for (int c = 0; c < 10; ++c) {
        float v;
        if (flag) v = bc[c];
        else
          v = lg[c] + satt0 * wsf[OFF_CB + c] + satt1 * wsf[OFF_CB + 10 + c] +
              wsf[OFF_C10 + c];
        out[(size_t)n * 10 + c] = v;
      }
    }
  }
}

// ---------------------------------------------------------------------------
extern "C" void kernel_launch(void* const* d_in, const int* in_sizes, int n_in,
                              void* d_out, int out_size, void* d_ws,
                              size_t ws_size, hipStream_t stream)
{
  const void* node_data = d_in[0];
  const int* nbr_data = (const int*)d_in[1];
  const void* nbr_mask = d_in[2];
  const float* v_emb = (const float*)d_in[3];
  const float* r_emb = (const float*)d_in[4];
  const float* time_w = (const float*)d_in[5];
  const float* time_b = (const float*)d_in[6];
  const float* Wq = (const float*)d_in[7];
  const float* bq = (const float*)d_in[8];
  const float* Wk = (const float*)d_in[9];
  const float* bk = (const float*)d_in[10];
  const float* bv = (const float*)d_in[12];
  const float* Wv = (const float*)d_in[11];
  const float* Wo = (const float*)d_in[13];
  const float* bo = (const float*)d_in[14];
  const float* Wc = (const float*)d_in[15];
  const float* bc = (const float*)d_in[16];
  float* out = (float*)d_out;
  float* wsf = (float*)d_ws;
  int* flags = (int*)((char*)d_ws + OFF_FLAGS * sizeof(float));

  unsigned short* ABC = (unsigned short*)((char*)d_ws + OFF_ABC);
  float* QBK = (float*)((char*)d_ws + OFF_QBK);
  unsigned* vbf = (unsigned*)((char*)d_ws + OFF_VBF);
  unsigned* rbf = (unsigned*)((char*)d_ws + OFF_RBF);

  hipLaunchKernelGGL(tgn_detect, dim3(1), dim3(256), 0, stream,
                     (const int*)node_data, (const unsigned char*)nbr_mask,
                     flags);
  hipLaunchKernelGGL(tgn_k0_prep, dim3(1), dim3(256), 0, stream, Wq, bq,
                     time_b, Wv, bv, Wo, bo, Wc, bc, wsf);
  hipLaunchKernelGGL(tgn_cvt, dim3(2048), dim3(256), 0, stream, v_emb, vbf,
                     100000 * 64);
  hipLaunchKernelGGL(tgn_cvt, dim3(2048), dim3(256), 0, stream, r_emb, rbf,
                     100000 * 64);
  hipLaunchKernelGGL(tgn_k1_abc, dim3(3125), dim3(256), 12416 * sizeof(float),
                     stream, node_data, v_emb, Wq, Wk, bk, wsf, flags, ABC,
                     QBK);
  hipLaunchKernelGGL(tgn_k2_edge, dim3(2500), dim3(256), 0, stream, node_data,
                     nbr_data, nbr_mask, vbf, rbf, time_w, time_b,
                     (const unsigned*)ABC, QBK, wsf, bc, flags, out);
}